// Round 5
// baseline (3063.094 us; speedup 1.0000x reference)
//
#include <hip/hip_runtime.h>
#include <hip/hip_bf16.h>
#include <cstddef>

// Problem constants
#define VOCAB 50000
#define D_EMB 512
#define HDIM  512
#define MDIM  512
#define BATCH 1024
#define SEQL  64
#define ROWS  2048          // 2 inputs * BATCH
#define KTOT  1024          // [x(512) | h(512)]
#define HC_K  3136          // 3073 padded to 49*64

typedef _Float16 f16;
typedef __attribute__((ext_vector_type(8))) _Float16 f16x8;
typedef __attribute__((ext_vector_type(4))) float f32x4;

__device__ __forceinline__ float sigf(float x) {
    return 1.0f / (1.0f + __expf(-x));
}
__device__ __forceinline__ float tanh_fast(float x) {
    x = fminf(30.0f, fmaxf(-30.0f, x));
    float t = __expf(-2.0f * x);
    return (1.0f - t) / (1.0f + t);
}
__device__ __forceinline__ void glds16(const void* g, const void* lds) {
    __builtin_amdgcn_global_load_lds(
        (const __attribute__((address_space(1))) unsigned int*)g,
        (__attribute__((address_space(3))) unsigned int*)lds, 16, 0, 0);
}

// ---------------------------------------------------------------------------
// Convert embedding table fp32 -> fp16 (8 elems/thread)
// ---------------------------------------------------------------------------
__global__ __launch_bounds__(256) void conv_emb(const float* __restrict__ src,
                                                f16* __restrict__ dst, int n8) {
    int i = blockIdx.x * 256 + threadIdx.x;
    if (i >= n8) return;
    const float4* s = (const float4*)src + (size_t)i * 2;
    float4 a = s[0], b = s[1];
    f16x8 o = {(f16)a.x, (f16)a.y, (f16)a.z, (f16)a.w,
               (f16)b.x, (f16)b.y, (f16)b.z, (f16)b.w};
    *(f16x8*)&dst[(size_t)i * 8] = o;
}

// ---------------------------------------------------------------------------
// Pack LSTM weights: Wt[dir][col'][k]  (fp16), k = [Wx(512);Wh(512)]
// col' = 64*(n>>4) + g*16 + (n&15)  (gate g of cell n)
// ---------------------------------------------------------------------------
__global__ __launch_bounds__(256) void pack_w(const float* __restrict__ kfw,
                                              const float* __restrict__ kbw,
                                              f16* __restrict__ Wt) {
    unsigned idx = blockIdx.x * 256 + threadIdx.x;   // over 2*2048*1024
    int k    = idx & 1023;
    int colp = (idx >> 10) & 2047;
    int d    = idx >> 21;
    int cg = colp >> 6, g = (colp >> 4) & 3, ci = colp & 15;
    int n = cg * 16 + ci;
    const float* K = d ? kbw : kfw;
    Wt[idx] = (f16)K[(size_t)k * 2048 + g * 512 + n];
}

// ---------------------------------------------------------------------------
// Pack W1: W1t[col][k] fp16, k padded 3073 -> 3136 with zeros
// ---------------------------------------------------------------------------
__global__ __launch_bounds__(256) void pack_w1(const float* __restrict__ W1,
                                               f16* __restrict__ W1t) {
    int idx = blockIdx.x * 256 + threadIdx.x;        // over 512*3136
    if (idx >= 512 * HC_K) return;
    int k = idx % HC_K, c = idx / HC_K;
    W1t[idx] = (k < 3073) ? (f16)W1[(size_t)k * MDIM + c] : (f16)0.0f;
}

// ---------------------------------------------------------------------------
// Deterministic rank-sort of the 2048 (input,row) pairs by seqlen DESC
// (ties broken by original index). key = (s<<12) - i; rank = #{key_j > key_i}.
// int4-vectorized LDS broadcast scan.
// ---------------------------------------------------------------------------
__global__ __launch_bounds__(256) void sort_rows(const int* __restrict__ sl1,
                                                 const int* __restrict__ sl2,
                                                 int* __restrict__ perm,
                                                 int* __restrict__ inv,
                                                 int* __restrict__ Acnt) {
    __shared__ int s_sh[ROWS];
    int tid = threadIdx.x;
    for (int i = tid; i < ROWS; i += 256) {
        int b = i & (BATCH - 1);
        s_sh[i] = (i < BATCH) ? sl1[b] : sl2[b];
    }
    __syncthreads();
    int i = blockIdx.x * 256 + tid;
    int key = (s_sh[i] << 12) - i;
    int rank = 0;
#pragma unroll 4
    for (int j = 0; j < ROWS; j += 4) {
        int4 v = *(const int4*)&s_sh[j];
        rank += ((v.x << 12) - (j + 0)) > key;
        rank += ((v.y << 12) - (j + 1)) > key;
        rank += ((v.z << 12) - (j + 2)) > key;
        rank += ((v.w << 12) - (j + 3)) > key;
    }
    perm[rank] = i;
    inv[i] = rank;
    if (blockIdx.x == 0 && tid < SEQL) {
        int c = 0;
#pragma unroll 4
        for (int j = 0; j < ROWS; j += 4) {
            int4 v = *(const int4*)&s_sh[j];
            c += (v.x > tid) + (v.y > tid) + (v.z > tid) + (v.w > tid);
        }
        Acnt[tid] = c;
    }
}

// ---------------------------------------------------------------------------
// One LSTM timestep (both dirs, rows sorted by seqlen desc). 128x128 tile,
// BK=64, 4 waves (2x2), MFMA 16x16x32 f16.
// A (emb-gather / h) loaded DIRECT global->register in fragment layout with
// 1-ktile register prefetch (no LDS, no barrier dependency for A).
// B (weights) via glds16 double-buffer with XOR-swizzled source+read.
// Row-tiles beyond the active prefix exit immediately.
// ---------------------------------------------------------------------------
__global__ __launch_bounds__(256, 2) void lstm_step(
    int t,
    const int* __restrict__ in1, const int* __restrict__ in2,
    const int* __restrict__ sl1, const int* __restrict__ sl2,
    const int* __restrict__ perm, const int* __restrict__ Acnt,
    const f16* __restrict__ embH,   // [VOCAB][512]
    const f16* __restrict__ Wt,     // [2][2048 col'][1024 k]
    const float* __restrict__ bfw, const float* __restrict__ bbw,
    const f16* __restrict__ hin,    // [2][2048][512] physical(sorted) rows
    f16* __restrict__ hout,
    float* __restrict__ cbuf)       // [2][2048][512] fp32
{
    const int by  = blockIdx.y;    // row tile (0..15)
    if (by * 128 >= Acnt[t]) return;   // whole tile inactive
    const int dir = blockIdx.z;
    const int bx  = blockIdx.x;    // col tile (0..15)
    const int tid = threadIdx.x;
    const int l = tid & 63, w = tid >> 6;

    __shared__ f16 Btile[2][128 * 64];   // 16 KB each
    __shared__ int toks[128];
    __shared__ int slens[128];

    if (tid < 128) {
        int r = perm[by * 128 + tid];       // original (input,row) id
        int b = r & (BATCH - 1);
        const int* inp = (r < BATCH) ? in1 : in2;
        int s = (r < BATCH) ? sl1[b] : sl2[b];
        int tt = t;
        if (dir == 1) tt = (t < s) ? (s - 1 - t) : t;
        toks[tid]  = inp[b * SEQL + tt];
        slens[tid] = s;
    }
    __syncthreads();

    // ---- B staging constants (glds16, swizzled source)
    const int kg8 = (((l & 7) ^ ((l >> 3) & 7))) * 8;   // swizzled k offset (f16)
    size_t boff[4]; int dstB[4];
#pragma unroll
    for (int r = 0; r < 4; ++r) {
        int row = r * 32 + w * 8 + (l >> 3);
        boff[r] = ((size_t)(dir * 2048 + bx * 128 + row) << 10) + kg8;
        dstB[r] = (r * 32 + w * 8) * 64;    // wave-uniform LDS base (f16 units)
    }

    const int wr = w >> 1, wc = w & 1;

    // ---- A per-lane fragment bases: row = wr*64 + fm*16 + (l&15)
    const int koff = (l >> 4) * 8;
    const f16* aEmb[4]; const f16* aH[4];
#pragma unroll
    for (int fm = 0; fm < 4; ++fm) {
        int row = wr * 64 + fm * 16 + (l & 15);
        aEmb[fm] = embH + (size_t)toks[row] * 512 + koff;
        aH[fm]   = hin + ((size_t)(dir * ROWS + by * 128 + row) << 9) + koff;
    }

    f32x4 acc[4][4];
#pragma unroll
    for (int i = 0; i < 4; ++i)
#pragma unroll
        for (int j = 0; j < 4; ++j) acc[i][j] = (f32x4){0.f, 0.f, 0.f, 0.f};

    f16x8 aF[2][4][2];   // [kt parity][fm][kk] — all indices static after unroll

    // prologue: A-frags for kt=0 (emb region), stage B k-tile 0 into buf 0
#pragma unroll
    for (int fm = 0; fm < 4; ++fm)
#pragma unroll
        for (int kk = 0; kk < 2; ++kk)
            aF[0][fm][kk] = *(const f16x8*)(aEmb[fm] + kk * 32);
#pragma unroll
    for (int r = 0; r < 4; ++r)
        glds16(Wt + boff[r], &Btile[0][dstB[r]]);
    __syncthreads();

#pragma unroll
    for (int kt = 0; kt < 16; ++kt) {
        const int cur = kt & 1;
        // ---- prefetch B[kt+1] (LDS dbuf) and A[kt+1] (registers)
        if (kt < 15) {
#pragma unroll
            for (int r = 0; r < 4; ++r)
                glds16(Wt + boff[r] + (kt + 1) * 64, &Btile[cur ^ 1][dstB[r]]);
#pragma unroll
            for (int fm = 0; fm < 4; ++fm)
#pragma unroll
                for (int kk = 0; kk < 2; ++kk)
                    aF[cur ^ 1][fm][kk] = (kt + 1 < 8)
                        ? *(const f16x8*)(aEmb[fm] + (kt + 1) * 64 + kk * 32)
                        : *(const f16x8*)(aH[fm] + (kt + 1 - 8) * 64 + kk * 32);
        }
        // ---- compute current tile
#pragma unroll
        for (int kk = 0; kk < 2; ++kk) {
            f16x8 bv[4];
            const int slot = (l >> 4) + kk * 4;
#pragma unroll
            for (int fn = 0; fn < 4; ++fn) {
                int col = wc * 64 + fn * 16 + (l & 15);
                bv[fn] = *(const f16x8*)&Btile[cur][col * 64 + (slot ^ (col & 7)) * 8];
            }
#pragma unroll
            for (int fm = 0; fm < 4; ++fm)
#pragma unroll
                for (int fn = 0; fn < 4; ++fn)
                    acc[fm][fn] = __builtin_amdgcn_mfma_f32_16x16x32_f16(
                        aF[cur][fm][kk], bv[fn], acc[fm][fn], 0, 0, 0);
        }
        __syncthreads();   // drains prefetches + guards B buffer swap
    }

    // ---- fused LSTM epilogue: lane owns cell = bx*32 + wc*16 + (l&15),
    //      gate g = fragment fn; rows = wr*64 + fm*16 + (l>>4)*4 + reg
    const float* bias = dir ? bbw : bfw;
    const int cell = bx * 32 + wc * 16 + (l & 15);
    float bg[4];
#pragma unroll
    for (int g = 0; g < 4; ++g) bg[g] = bias[g * 512 + cell];

#pragma unroll
    for (int fm = 0; fm < 4; ++fm) {
#pragma unroll
        for (int reg = 0; reg < 4; ++reg) {
            int rl = wr * 64 + fm * 16 + (l >> 4) * 4 + reg;
            if (t < slens[rl]) {
                size_t idx = ((size_t)(dir * ROWS + by * 128 + rl) << 9) + cell;
                float gi = acc[fm][0][reg] + bg[0];
                float gj = acc[fm][1][reg] + bg[1];
                float gf = acc[fm][2][reg] + bg[2];
                float go = acc[fm][3][reg] + bg[3];
                float cold = cbuf[idx];
                float cn = cold * sigf(gf + 1.0f) + sigf(gi) * tanh_fast(gj);
                float hn = tanh_fast(cn) * sigf(go);
                cbuf[idx] = cn;
                hout[idx] = (f16)hn;
            }
        }
    }
}

// ---------------------------------------------------------------------------
// Build h_combined fp16 [1024][3136] = [h1, h2, dist, h1*h2, 0-pad].
// Final h of row r lives in parity buffer (s_r & 1) at sorted position inv[r].
// ---------------------------------------------------------------------------
__global__ __launch_bounds__(256) void build_hc(const f16* __restrict__ hbuf0,
                                                const f16* __restrict__ hbuf1,
                                                const int* __restrict__ sl1,
                                                const int* __restrict__ sl2,
                                                const int* __restrict__ inv,
                                                f16* __restrict__ hc) {
    int b = blockIdx.x;
    int tid = threadIdx.x;
    __shared__ float red[256];
    int s1 = sl1[b], s2 = sl2[b];
    int p1 = inv[b], p2 = inv[BATCH + b];
    const f16* hf1 = (s1 & 1) ? hbuf1 : hbuf0;
    const f16* hf2 = (s2 & 1) ? hbuf1 : hbuf0;
    float d = 0.0f;
    size_t base = (size_t)b * HC_K;
    for (int k = tid; k < 1024; k += 256) {
        int dir = k >> 9, kk = k & 511;
        float h1 = (float)hf1[((size_t)(dir * ROWS + p1) << 9) + kk];
        float h2 = (float)hf2[((size_t)(dir * ROWS + p2) << 9) + kk];
        hc[base + k]        = (f16)h1;
        hc[base + 1024 + k] = (f16)h2;
        hc[base + 2049 + k] = (f16)(h1 * h2);
        float df = h1 - h2;
        d += df * df;
    }
    red[tid] = d;
    __syncthreads();
    for (int s = 128; s > 0; s >>= 1) {
        if (tid < s) red[tid] += red[tid + s];
        __syncthreads();
    }
    if (tid == 0) hc[base + 2048] = (f16)red[0];
    if (tid < HC_K - 3073) hc[base + 3073 + tid] = (f16)0.0f;
}

// ---------------------------------------------------------------------------
// e1 = relu(hc @ W1 + b1)   fp16 MFMA, 64x64 tile, BK=64, 4 waves (2x2),
// 2-phase double-buffered staging. K = 3136 (49 tiles).
// ---------------------------------------------------------------------------
__global__ __launch_bounds__(256) void mlp1(const f16* __restrict__ hc,
                                            const f16* __restrict__ W1t,
                                            const float* __restrict__ b1,
                                            float* __restrict__ e1) {
    const int bx = blockIdx.x, by = blockIdx.y, tid = threadIdx.x;
    const int l = tid & 63, w = tid >> 6;
    __shared__ f16 Atile[2][64 * 64];   // 8 KB each
    __shared__ f16 Btile[2][64 * 64];

    const int kg8 = (((l & 7) ^ ((l >> 3) & 7))) * 8;
    size_t aoff[2], boff[2]; int dst[2];
#pragma unroll
    for (int g = 0; g < 2; ++g) {
        int row = g * 32 + w * 8 + (l >> 3);
        aoff[g] = (size_t)(by * 64 + row) * HC_K + kg8;
        boff[g] = (size_t)(bx * 64 + row) * HC_K + kg8;
        dst[g]  = (g * 32 + w * 8) * 64;
    }

    f32x4 acc[2][2];
#pragma unroll
    for (int i = 0; i < 2; ++i)
#pragma unroll
        for (int j = 0; j < 2; ++j) acc[i][j] = (f32x4){0.f, 0.f, 0.f, 0.f};

    const int wr = w >> 1, wc = w & 1;

#pragma unroll
    for (int g = 0; g < 2; ++g) {
        glds16(hc + aoff[g], &Atile[0][dst[g]]);
        glds16(W1t + boff[g], &Btile[0][dst[g]]);
    }
    __syncthreads();

    int cur = 0;
    for (int kt = 0; kt < HC_K / 64; ++kt) {
        if (kt < HC_K / 64 - 1) {
            const int kn = (kt + 1) * 64;
#pragma unroll
            for (int g = 0; g < 2; ++g) {
                glds16(hc + aoff[g] + kn, &Atile[cur ^ 1][dst[g]]);
                glds16(W1t + boff[g] + kn, &Btile[cur ^ 1][dst[g]]);
            }
        }
#pragma unroll
        for (int kk = 0; kk < 2; ++kk) {
            f16x8 af[2], bv[2];
            const int slot = (l >> 4) + kk * 4;
#pragma unroll
            for (int fm = 0; fm < 2; ++fm) {
                int row = wr * 32 + fm * 16 + (l & 15);
                af[fm] = *(const f16x8*)&Atile[cur][row * 64 + (slot ^ (row & 7)) * 8];
            }
#pragma unroll
            for (int fn = 0; fn < 2; ++fn) {
                int col = wc * 32 + fn * 16 + (l & 15);
                bv[fn] = *(const f16x8*)&Btile[cur][col * 64 + (slot ^ (col & 7)) * 8];
            }
#pragma unroll
            for (int fm = 0; fm < 2; ++fm)
#pragma unroll
                for (int fn = 0; fn < 2; ++fn)
                    acc[fm][fn] = __builtin_amdgcn_mfma_f32_16x16x32_f16(
                        af[fm], bv[fn], acc[fm][fn], 0, 0, 0);
        }
        __syncthreads();
        cur ^= 1;
    }

#pragma unroll
    for (int fm = 0; fm < 2; ++fm) {
#pragma unroll
        for (int fn = 0; fn < 2; ++fn) {
#pragma unroll
            for (int reg = 0; reg < 4; ++reg) {
                int r = by * 64 + wr * 32 + fm * 16 + (l >> 4) * 4 + reg;
                int c = bx * 64 + wc * 32 + fn * 16 + (l & 15);
                float v = acc[fm][fn][reg] + b1[c];
                e1[(size_t)r * MDIM + c] = v > 0.0f ? v : 0.0f;
            }
        }
    }
}

// ---------------------------------------------------------------------------
// preds = e1 @ W2 + b2   [1024 x 512] @ [512 x 2]
// ---------------------------------------------------------------------------
__global__ __launch_bounds__(64) void mlp2(const float* __restrict__ e1,
                                           const float* __restrict__ W2,
                                           const float* __restrict__ b2,
                                           float* __restrict__ out) {
    int b = blockIdx.x, tid = threadIdx.x;
    float p0 = 0.f, p1 = 0.f;
    for (int k = tid; k < 512; k += 64) {
        float e = e1[(size_t)b * MDIM + k];
        p0 += e * W2[2 * k];
        p1 += e * W2[2 * k + 1];
    }
    for (int off = 32; off > 0; off >>= 1) {
        p0 += __shfl_down(p0, off);
        p1 += __shfl_down(p1, off);
    }
    if (tid == 0) {
        out[2 * b]     = p0 + b2[0];
        out[2 * b + 1] = p1 + b2[1];
    }
}

// ---------------------------------------------------------------------------
extern "C" void kernel_launch(void* const* d_in, const int* in_sizes, int n_in,
                              void* d_out, int out_size, void* d_ws, size_t ws_size,
                              hipStream_t stream) {
    (void)in_sizes; (void)n_in; (void)out_size; (void)ws_size;
    const int*   in1 = (const int*)d_in[0];
    const int*   in2 = (const int*)d_in[1];
    const int*   sl1 = (const int*)d_in[2];
    const int*   sl2 = (const int*)d_in[3];
    const float* emb = (const float*)d_in[4];
    const float* kfw = (const float*)d_in[5];
    const float* bfw = (const float*)d_in[6];
    const float* kbw = (const float*)d_in[7];
    const float* bbw = (const float*)d_in[8];
    const float* W1  = (const float*)d_in[9];
    const float* b1  = (const float*)d_in[10];
    const float* W2  = (const float*)d_in[11];
    const float* b2  = (const float*)d_in[12];
    float* out = (float*)d_out;

    char* base = (char*)d_ws;
    f16*   embH = (f16*)base;                      // 51,200,000 B
    f16*   Wt   = (f16*)(base + 51200000);         //  8,388,608 B
    f16*   W1t  = (f16*)(base + 59588608);         //  3,211,264 B
    float* cbuf = (float*)(base + 62799872);       //  8,388,608 B
    f16*   h0   = (f16*)(base + 71188480);         //  4,194,304 B
    f16*   h1   = (f16*)(base + 75382784);         //  4,194,304 B
    f16*   hc   = (f16*)(base + 79577088);         //  6,422,528 B
    float* e1   = (float*)(base + 85999616);       //  2,097,152 B
    int*   perm = (int*)(base + 88096768);         //      8,192 B
    int*   inv  = (int*)(base + 88104960);         //      8,192 B
    int*   Acnt = (int*)(base + 88113152);         //        256 B

    // zero c and h0 (initial state)
    hipMemsetAsync(cbuf, 0, 8388608, stream);
    hipMemsetAsync(h0, 0, 4194304, stream);

    sort_rows<<<ROWS / 256, 256, 0, stream>>>(sl1, sl2, perm, inv, Acnt);
    conv_emb<<<(VOCAB * D_EMB / 8 + 255) / 256, 256, 0, stream>>>(emb, embH, VOCAB * D_EMB / 8);
    pack_w<<<(2 * 2048 * KTOT) / 256, 256, 0, stream>>>(kfw, kbw, Wt);
    pack_w1<<<(512 * HC_K + 255) / 256, 256, 0, stream>>>(W1, W1t);

    for (int t = 0; t < SEQL; ++t) {
        const f16* hi = (t & 1) ? h1 : h0;   // buf[t&1]
        f16*       ho = (t & 1) ? h0 : h1;   // buf[(t+1)&1]
        lstm_step<<<dim3(16, 16, 2), 256, 0, stream>>>(
            t, in1, in2, sl1, sl2, perm, Acnt, embH, Wt, bfw, bbw, hi, ho, cbuf);
    }

    build_hc<<<BATCH, 256, 0, stream>>>(h0, h1, sl1, sl2, inv, hc);
    mlp1<<<dim3(MDIM / 64, BATCH / 64), 256, 0, stream>>>(hc, W1t, b1, e1);
    mlp2<<<BATCH, 64, 0, stream>>>(e1, W2, b2, out);
}

// Round 7
// 2383.910 us; speedup vs baseline: 1.2849x; 1.2849x over previous
//
#include <hip/hip_runtime.h>
#include <hip/hip_bf16.h>
#include <cstddef>

// Problem constants
#define VOCAB 50000
#define D_EMB 512
#define HDIM  512
#define MDIM  512
#define BATCH 1024
#define SEQL  64
#define ROWS  2048          // 2 inputs * BATCH
#define HC_K  3136          // 3073 padded to 49*64

typedef _Float16 f16;
typedef __attribute__((ext_vector_type(8))) _Float16 f16x8;
typedef __attribute__((ext_vector_type(4))) float f32x4;

__device__ __forceinline__ float sigf(float x) {
    return 1.0f / (1.0f + __expf(-x));
}
__device__ __forceinline__ float tanh_fast(float x) {
    x = fminf(30.0f, fmaxf(-30.0f, x));
    float t = __expf(-2.0f * x);
    return (1.0f - t) / (1.0f + t);
}
__device__ __forceinline__ void glds16(const void* g, const void* lds) {
    __builtin_amdgcn_global_load_lds(
        (const __attribute__((address_space(1))) unsigned int*)g,
        (__attribute__((address_space(3))) unsigned int*)lds, 16, 0, 0);
}

// ---------------------------------------------------------------------------
// fp32 -> fp16 embedding convert
// ---------------------------------------------------------------------------
__global__ __launch_bounds__(256) void conv_emb(const float* __restrict__ src,
                                                f16* __restrict__ dst, int n8) {
    int i = blockIdx.x * 256 + threadIdx.x;
    if (i >= n8) return;
    const float4* s = (const float4*)src + (size_t)i * 2;
    float4 a = s[0], b = s[1];
    f16x8 o = {(f16)a.x, (f16)a.y, (f16)a.z, (f16)a.w,
               (f16)b.x, (f16)b.y, (f16)b.z, (f16)b.w};
    *(f16x8*)&dst[(size_t)i * 8] = o;
}

// ---------------------------------------------------------------------------
// Pack LSTM weights: Wt[dir][col'][k] (fp16), k = [Wx(512);Wh(512)]
// col' = 64*(n>>4) + g*16 + (n&15)
// ---------------------------------------------------------------------------
__global__ __launch_bounds__(256) void pack_w(const float* __restrict__ kfw,
                                              const float* __restrict__ kbw,
                                              f16* __restrict__ Wt) {
    unsigned idx = blockIdx.x * 256 + threadIdx.x;   // over 2*2048*1024
    int k    = idx & 1023;
    int colp = (idx >> 10) & 2047;
    int d    = idx >> 21;
    int cg = colp >> 6, g = (colp >> 4) & 3, ci = colp & 15;
    int n = cg * 16 + ci;
    const float* K = d ? kbw : kfw;
    Wt[idx] = (f16)K[(size_t)k * 2048 + g * 512 + n];
}

// ---------------------------------------------------------------------------
// Pack W1: W1t[col][k] fp16, k padded 3073 -> 3136
// ---------------------------------------------------------------------------
__global__ __launch_bounds__(256) void pack_w1(const float* __restrict__ W1,
                                               f16* __restrict__ W1t) {
    int idx = blockIdx.x * 256 + threadIdx.x;
    if (idx >= 512 * HC_K) return;
    int k = idx % HC_K, c = idx / HC_K;
    W1t[idx] = (k < 3073) ? (f16)W1[(size_t)k * MDIM + c] : (f16)0.0f;
}

// ---------------------------------------------------------------------------
// Deterministic rank-sort by seqlen DESC (tie: original index asc).
// ---------------------------------------------------------------------------
__global__ __launch_bounds__(256) void sort_rows(const int* __restrict__ sl1,
                                                 const int* __restrict__ sl2,
                                                 int* __restrict__ perm,
                                                 int* __restrict__ inv,
                                                 int* __restrict__ Acnt) {
    __shared__ int s_sh[ROWS];
    int tid = threadIdx.x;
    for (int i = tid; i < ROWS; i += 256) {
        int b = i & (BATCH - 1);
        s_sh[i] = (i < BATCH) ? sl1[b] : sl2[b];
    }
    __syncthreads();
    int i = blockIdx.x * 256 + tid;
    int key = (s_sh[i] << 12) - i;
    int rank = 0;
#pragma unroll 4
    for (int j = 0; j < ROWS; j += 4) {
        int4 v = *(const int4*)&s_sh[j];
        rank += ((v.x << 12) - (j + 0)) > key;
        rank += ((v.y << 12) - (j + 1)) > key;
        rank += ((v.z << 12) - (j + 2)) > key;
        rank += ((v.w << 12) - (j + 3)) > key;
    }
    perm[rank] = i;
    inv[i] = rank;
    if (blockIdx.x == 0 && tid < SEQL) {
        int c = 0;
#pragma unroll 4
        for (int j = 0; j < ROWS; j += 4) {
            int4 v = *(const int4*)&s_sh[j];
            c += (v.x > tid) + (v.y > tid) + (v.z > tid) + (v.w > tid);
        }
        Acnt[tid] = c;
    }
}

// ---------------------------------------------------------------------------
// One LSTM timestep. Tile 128 rows x 256 cols, BK=64, 4 waves (2x2),
// MFMA 16x16x32 f16. 3-buffer LDS staging with 2-deep prefetch and
// COUNTED vmcnt (never drained to 0 in the main loop) + raw s_barrier.
// 12 glds16 per thread per k-tile (4 A + 8 B), XOR-swizzled src+read.
// Row-tiles beyond the active prefix (seqlen-sorted) exit immediately.
// ---------------------------------------------------------------------------
__global__ __launch_bounds__(256, 1) void lstm_step(
    int t,
    const int* __restrict__ in1, const int* __restrict__ in2,
    const int* __restrict__ sl1, const int* __restrict__ sl2,
    const int* __restrict__ perm, const int* __restrict__ Acnt,
    const f16* __restrict__ embH,   // [VOCAB][512]
    const f16* __restrict__ Wt,     // [2][2048 col'][1024 k]
    const float* __restrict__ bfw, const float* __restrict__ bbw,
    const f16* __restrict__ hin,    // [2][2048][512] sorted rows
    f16* __restrict__ hout,
    float* __restrict__ cbuf)       // [2][2048][512] fp32
{
    const int by = blockIdx.y;              // row tile (0..15)
    if (by * 128 >= Acnt[t]) return;
    const int dir = blockIdx.z;
    const int bx  = blockIdx.x;             // col tile (0..7), 256 cols
    const int tid = threadIdx.x;
    const int l = tid & 63, w = tid >> 6;

    __shared__ f16 At[3][128 * 64];         // 48 KB
    __shared__ f16 Bt[3][256 * 64];         // 96 KB
    __shared__ int toks[128];
    __shared__ int slens[128];

    if (tid < 128) {
        int r = perm[by * 128 + tid];
        int b = r & (BATCH - 1);
        const int* inp = (r < BATCH) ? in1 : in2;
        int s = (r < BATCH) ? sl1[b] : sl2[b];
        int tt = t;
        if (dir == 1) tt = (t < s) ? (s - 1 - t) : t;
        toks[tid]  = inp[b * SEQL + tt];
        slens[tid] = s;
    }
    __syncthreads();

    // staging constants (swizzled source chunk per lane)
    const int kg8 = (((l & 7) ^ ((l >> 3) & 7))) * 8;
    int aoffX[4], hoff[4], dstA[4];
#pragma unroll
    for (int r = 0; r < 4; ++r) {
        int row = r * 32 + w * 8 + (l >> 3);
        aoffX[r] = toks[row] * 512 + kg8;
        hoff[r]  = ((dir * ROWS + by * 128 + row) << 9) + kg8;
        dstA[r]  = (r * 32 + w * 8) * 64;   // wave-uniform LDS base
    }
    size_t boff[8]; int dstB[8];
#pragma unroll
    for (int r = 0; r < 8; ++r) {
        int row = r * 32 + w * 8 + (l >> 3);      // B col 0..255
        boff[r] = ((size_t)(dir * 2048 + bx * 256 + row) << 10) + kg8;
        dstB[r] = (r * 32 + w * 8) * 64;
    }

#define STAGE(KT, BUF)                                                       \
    {                                                                        \
        const int kt_ = (KT);                                                \
        _Pragma("unroll") for (int r_ = 0; r_ < 4; ++r_) {                   \
            const f16* asrc = (kt_ < 8)                                      \
                ? (embH + aoffX[r_] + kt_ * 64)                              \
                : (hin + hoff[r_] + (kt_ - 8) * 64);                         \
            glds16(asrc, &At[BUF][dstA[r_]]);                                \
        }                                                                    \
        _Pragma("unroll") for (int r_ = 0; r_ < 8; ++r_)                     \
            glds16(Wt + boff[r_] + kt_ * 64, &Bt[BUF][dstB[r_]]);            \
    }

    const int wr = w >> 1, wc = w & 1;

    f32x4 acc[4][8];
#pragma unroll
    for (int i = 0; i < 4; ++i)
#pragma unroll
        for (int j = 0; j < 8; ++j) acc[i][j] = (f32x4){0.f, 0.f, 0.f, 0.f};

    // prologue: 2-deep prefetch
    STAGE(0, 0)
    STAGE(1, 1)

    int cb = 0;   // kt % 3
#pragma unroll 1
    for (int kt = 0; kt < 16; ++kt) {
        // counted wait: leave the 12 loads of tile kt+1 in flight
        if (kt == 15) { asm volatile("s_waitcnt vmcnt(0)" ::: "memory"); }
        else         { asm volatile("s_waitcnt vmcnt(12)" ::: "memory"); }
        __builtin_amdgcn_s_barrier();
        if (kt < 14) {
            int nb = cb + 2; if (nb >= 3) nb -= 3;
            STAGE(kt + 2, nb)
        }
#pragma unroll
        for (int kk = 0; kk < 2; ++kk) {
            f16x8 af[4], bv[8];
            const int slot = (l >> 4) + kk * 4;
#pragma unroll
            for (int fm = 0; fm < 4; ++fm) {
                int row = wr * 64 + fm * 16 + (l & 15);
                af[fm] = *(const f16x8*)&At[cb][row * 64 + (slot ^ (row & 7)) * 8];
            }
#pragma unroll
            for (int fn = 0; fn < 8; ++fn) {
                int col = wc * 128 + fn * 16 + (l & 15);
                bv[fn] = *(const f16x8*)&Bt[cb][col * 64 + (slot ^ (col & 7)) * 8];
            }
#pragma unroll
            for (int fm = 0; fm < 4; ++fm)
#pragma unroll
                for (int fn = 0; fn < 8; ++fn)
                    acc[fm][fn] = __builtin_amdgcn_mfma_f32_16x16x32_f16(
                        af[fm], bv[fn], acc[fm][fn], 0, 0, 0);
        }
        cb = (cb == 2) ? 0 : cb + 1;
    }
#undef STAGE

    // ---- fused LSTM epilogue: lane owns cells c2=0..1:
    //      cell = bx*64 + (wc*2+c2)*16 + (l&15); gate g = acc[..][c2*4+g]
    //      rows rl = wr*64 + fm*16 + (l>>4)*4 + reg
    const float* bias = dir ? bbw : bfw;
    const int ci = l & 15;
    float bg[2][4];
    int cells[2];
#pragma unroll
    for (int c2 = 0; c2 < 2; ++c2) {
        cells[c2] = bx * 64 + (wc * 2 + c2) * 16 + ci;
#pragma unroll
        for (int g = 0; g < 4; ++g) bg[c2][g] = bias[g * 512 + cells[c2]];
    }
#pragma unroll
    for (int fm = 0; fm < 4; ++fm) {
#pragma unroll
        for (int reg = 0; reg < 4; ++reg) {
            int rl = wr * 64 + fm * 16 + (l >> 4) * 4 + reg;
            if (t < slens[rl]) {
                size_t rbase = (size_t)(dir * ROWS + by * 128 + rl) << 9;
#pragma unroll
                for (int c2 = 0; c2 < 2; ++c2) {
                    size_t idx = rbase + cells[c2];
                    float gi = acc[fm][c2 * 4 + 0][reg] + bg[c2][0];
                    float gj = acc[fm][c2 * 4 + 1][reg] + bg[c2][1];
                    float gf = acc[fm][c2 * 4 + 2][reg] + bg[c2][2];
                    float go = acc[fm][c2 * 4 + 3][reg] + bg[c2][3];
                    float cold = cbuf[idx];
                    float cn = cold * sigf(gf + 1.0f) + sigf(gi) * tanh_fast(gj);
                    float hn = tanh_fast(cn) * sigf(go);
                    cbuf[idx] = cn;
                    hout[idx] = (f16)hn;
                }
            }
        }
    }
}

// ---------------------------------------------------------------------------
// Build h_combined fp16 [1024][3136]; final h at parity buffer (s&1), row inv[r].
// ---------------------------------------------------------------------------
__global__ __launch_bounds__(256) void build_hc(const f16* __restrict__ hbuf0,
                                                const f16* __restrict__ hbuf1,
                                                const int* __restrict__ sl1,
                                                const int* __restrict__ sl2,
                                                const int* __restrict__ inv,
                                                f16* __restrict__ hc) {
    int b = blockIdx.x;
    int tid = threadIdx.x;
    __shared__ float red[256];
    int s1 = sl1[b], s2 = sl2[b];
    int p1 = inv[b], p2 = inv[BATCH + b];
    const f16* hf1 = (s1 & 1) ? hbuf1 : hbuf0;
    const f16* hf2 = (s2 & 1) ? hbuf1 : hbuf0;
    float d = 0.0f;
    size_t base = (size_t)b * HC_K;
    for (int k = tid; k < 1024; k += 256) {
        int dir = k >> 9, kk = k & 511;
        float h1 = (float)hf1[((size_t)(dir * ROWS + p1) << 9) + kk];
        float h2 = (float)hf2[((size_t)(dir * ROWS + p2) << 9) + kk];
        hc[base + k]        = (f16)h1;
        hc[base + 1024 + k] = (f16)h2;
        hc[base + 2049 + k] = (f16)(h1 * h2);
        float df = h1 - h2;
        d += df * df;
    }
    red[tid] = d;
    __syncthreads();
    for (int s = 128; s > 0; s >>= 1) {
        if (tid < s) red[tid] += red[tid + s];
        __syncthreads();
    }
    if (tid == 0) hc[base + 2048] = (f16)red[0];
    if (tid < HC_K - 3073) hc[base + 3073 + tid] = (f16)0.0f;
}

// ---------------------------------------------------------------------------
// e1 = relu(hc @ W1 + b1)  fp16 MFMA 64x64 tile, BK=64, dbuf
// ---------------------------------------------------------------------------
__global__ __launch_bounds__(256) void mlp1(const f16* __restrict__ hc,
                                            const f16* __restrict__ W1t,
                                            const float* __restrict__ b1,
                                            float* __restrict__ e1) {
    const int bx = blockIdx.x, by = blockIdx.y, tid = threadIdx.x;
    const int l = tid & 63, w = tid >> 6;
    __shared__ f16 Atile[2][64 * 64];
    __shared__ f16 Btile[2][64 * 64];

    const int kg8 = (((l & 7) ^ ((l >> 3) & 7))) * 8;
    size_t aoff[2], boff[2]; int dst[2];
#pragma unroll
    for (int g = 0; g < 2; ++g) {
        int row = g * 32 + w * 8 + (l >> 3);
        aoff[g] = (size_t)(by * 64 + row) * HC_K + kg8;
        boff[g] = (size_t)(bx * 64 + row) * HC_K + kg8;
        dst[g]  = (g * 32 + w * 8) * 64;
    }

    f32x4 acc[2][2];
#pragma unroll
    for (int i = 0; i < 2; ++i)
#pragma unroll
        for (int j = 0; j < 2; ++j) acc[i][j] = (f32x4){0.f, 0.f, 0.f, 0.f};

    const int wr = w >> 1, wc = w & 1;

#pragma unroll
    for (int g = 0; g < 2; ++g) {
        glds16(hc + aoff[g], &Atile[0][dst[g]]);
        glds16(W1t + boff[g], &Btile[0][dst[g]]);
    }
    __syncthreads();

    int cur = 0;
    for (int kt = 0; kt < HC_K / 64; ++kt) {
        if (kt < HC_K / 64 - 1) {
            const int kn = (kt + 1) * 64;
#pragma unroll
            for (int g = 0; g < 2; ++g) {
                glds16(hc + aoff[g] + kn, &Atile[cur ^ 1][dst[g]]);
                glds16(W1t + boff[g] + kn, &Btile[cur ^ 1][dst[g]]);
            }
        }
#pragma unroll
        for (int kk = 0; kk < 2; ++kk) {
            f16x8 af[2], bv[2];
            const int slot = (l >> 4) + kk * 4;
#pragma unroll
            for (int fm = 0; fm < 2; ++fm) {
                int row = wr * 32 + fm * 16 + (l & 15);
                af[fm] = *(const f16x8*)&Atile[cur][row * 64 + (slot ^ (row & 7)) * 8];
            }
#pragma unroll
            for (int fn = 0; fn < 2; ++fn) {
                int col = wc * 32 + fn * 16 + (l & 15);
                bv[fn] = *(const f16x8*)&Btile[cur][col * 64 + (slot ^ (col & 7)) * 8];
            }
#pragma unroll
            for (int fm = 0; fm < 2; ++fm)
#pragma unroll
                for (int fn = 0; fn < 2; ++fn)
                    acc[fm][fn] = __builtin_amdgcn_mfma_f32_16x16x32_f16(
                        af[fm], bv[fn], acc[fm][fn], 0, 0, 0);
        }
        __syncthreads();
        cur ^= 1;
    }

#pragma unroll
    for (int fm = 0; fm < 2; ++fm) {
#pragma unroll
        for (int fn = 0; fn < 2; ++fn) {
#pragma unroll
            for (int reg = 0; reg < 4; ++reg) {
                int r = by * 64 + wr * 32 + fm * 16 + (l >> 4) * 4 + reg;
                int c = bx * 64 + wc * 32 + fn * 16 + (l & 15);
                float v = acc[fm][fn][reg] + b1[c];
                e1[(size_t)r * MDIM + c] = v > 0.0f ? v : 0.0f;
            }
        }
    }
}

// ---------------------------------------------------------------------------
// preds = e1 @ W2 + b2
// ---------------------------------------------------------------------------
__global__ __launch_bounds__(64) void mlp2(const float* __restrict__ e1,
                                           const float* __restrict__ W2,
                                           const float* __restrict__ b2,
                                           float* __restrict__ out) {
    int b = blockIdx.x, tid = threadIdx.x;
    float p0 = 0.f, p1 = 0.f;
    for (int k = tid; k < 512; k += 64) {
        float e = e1[(size_t)b * MDIM + k];
        p0 += e * W2[2 * k];
        p1 += e * W2[2 * k + 1];
    }
    for (int off = 32; off > 0; off >>= 1) {
        p0 += __shfl_down(p0, off);
        p1 += __shfl_down(p1, off);
    }
    if (tid == 0) {
        out[2 * b]     = p0 + b2[0];
        out[2 * b + 1] = p1 + b2[1];
    }
}

// ---------------------------------------------------------------------------
extern "C" void kernel_launch(void* const* d_in, const int* in_sizes, int n_in,
                              void* d_out, int out_size, void* d_ws, size_t ws_size,
                              hipStream_t stream) {
    (void)in_sizes; (void)n_in; (void)out_size; (void)ws_size;
    const int*   in1 = (const int*)d_in[0];
    const int*   in2 = (const int*)d_in[1];
    const int*   sl1 = (const int*)d_in[2];
    const int*   sl2 = (const int*)d_in[3];
    const float* emb = (const float*)d_in[4];
    const float* kfw = (const float*)d_in[5];
    const float* bfw = (const float*)d_in[6];
    const float* kbw = (const float*)d_in[7];
    const float* bbw = (const float*)d_in[8];
    const float* W1  = (const float*)d_in[9];
    const float* b1  = (const float*)d_in[10];
    const float* W2  = (const float*)d_in[11];
    const float* b2  = (const float*)d_in[12];
    float* out = (float*)d_out;

    char* base = (char*)d_ws;
    f16*   embH = (f16*)base;                      // 51,200,000 B
    f16*   Wt   = (f16*)(base + 51200000);         //  8,388,608 B
    f16*   W1t  = (f16*)(base + 59588608);         //  3,211,264 B
    float* cbuf = (float*)(base + 62799872);       //  8,388,608 B
    f16*   h0   = (f16*)(base + 71188480);         //  4,194,304 B
    f16*   h1   = (f16*)(base + 75382784);         //  4,194,304 B
    f16*   hc   = (f16*)(base + 79577088);         //  6,422,528 B
    float* e1   = (float*)(base + 85999616);       //  2,097,152 B
    int*   perm = (int*)(base + 88096768);         //      8,192 B
    int*   inv  = (int*)(base + 88104960);         //      8,192 B
    int*   Acnt = (int*)(base + 88113152);         //        256 B

    // zero c and h0 (initial state)
    hipMemsetAsync(cbuf, 0, 8388608, stream);
    hipMemsetAsync(h0, 0, 4194304, stream);

    sort_rows<<<ROWS / 256, 256, 0, stream>>>(sl1, sl2, perm, inv, Acnt);
    conv_emb<<<(VOCAB * D_EMB / 8 + 255) / 256, 256, 0, stream>>>(emb, embH, VOCAB * D_EMB / 8);
    pack_w<<<(2 * 2048 * 1024) / 256, 256, 0, stream>>>(kfw, kbw, Wt);
    pack_w1<<<(512 * HC_K + 255) / 256, 256, 0, stream>>>(W1, W1t);

    for (int t = 0; t < SEQL; ++t) {
        const f16* hi = (t & 1) ? h1 : h0;   // buf[t&1]
        f16*       ho = (t & 1) ? h0 : h1;   // buf[(t+1)&1]
        lstm_step<<<dim3(8, 16, 2), 256, 0, stream>>>(
            t, in1, in2, sl1, sl2, perm, Acnt, embH, Wt, bfw, bbw, hi, ho, cbuf);
    }

    build_hc<<<BATCH, 256, 0, stream>>>(h0, h1, sl1, sl2, inv, hc);
    mlp1<<<dim3(MDIM / 64, BATCH / 64), 256, 0, stream>>>(hc, W1t, b1, e1);
    mlp2<<<BATCH, 64, 0, stream>>>(e1, W2, b2, out);
}